// Round 33
// baseline (63.622 us; speedup 1.0000x reference)
//
#include <hip/hip_runtime.h>
#include <utility>

#define D_DIM 256
#define BLKT  512                  // 8 waves: 2 col-halves x 4 row-groups
#define WID   33
#define CEN   16
#define RACC  4                    // output rows per thread
#define XROWS (RACC + 2 * CEN)     // 36 x-rows read per thread per iter
#define RITER 16                   // output rows per iteration (4 rg x 4)
#define NI    16                   // iterations per block
#define CHUNK (RITER * NI)         // 256 output rows per block
#define RING  64                   // ring rows = 64 KB LDS (2 blocks/CU)
#define PROL  48                   // prologue staged rows (= RITER + 32)

// R32 (55.3us): NT stores helped via write-path relief (FETCH unchanged ->
// L3-retention theory wrong, write backpressure theory fits). Still 20%
// occupancy, no pipe >60%. This round: 512-thread blocks on the SAME 64KB
// ring -> 2 blocks/CU x 8 waves = 16 waves/CU (2x TLP). Wave = 128-col
// half (f32x2) x 4-row group; per-output LDS bytes unchanged; readlane/elem
// 8.25->16.5 (+16% VALU, tolerable at 2x waves). All else R32-identical.

typedef float f32x2 __attribute__((ext_vector_type(2)));

__device__ __forceinline__ float rdlane(float v, int l) {
    return __uint_as_float(__builtin_amdgcn_readlane(__float_as_uint(v), l));
}

__device__ __forceinline__ int clampN(int p, int N) {
    return p < 0 ? 0 : (p >= N ? N - 1 : p);
}

__device__ __forceinline__ f32x2 ld2(const float* p) {
    return *(const f32x2*)p;
}

__device__ __forceinline__ void dma_row(float* xs, int slot,
                                        const float* __restrict__ xlane,
                                        int row) {
    __builtin_amdgcn_global_load_lds(
        (const __attribute__((address_space(1))) void*)(xlane +
                                                        (size_t)row * D_DIM),
        (__attribute__((address_space(3))) void*)(xs + slot * D_DIM), 16, 0, 0);
}

// prologue: 48 rows, 6 per wave
template <size_t... Ss>
__device__ __forceinline__ void stage_prol(float* xs,
                                           const float* __restrict__ xlane,
                                           int base0, int N, int wv,
                                           std::index_sequence<Ss...>) {
    (([&] {
         const int s = wv * (PROL / 8) + (int)Ss;
         dma_row(xs, s, xlane, clampN(base0 + s, N));
     }()),
     ...);
}

// stage 16 rows (2 per wave): row base0+48+16m+k -> slot (48+16m+k) & 63
__device__ __forceinline__ void stage_iter(float* xs,
                                           const float* __restrict__ xlane,
                                           int base0, int m, int N, int wv) {
#pragma unroll
    for (int kk = 0; kk < 2; ++kk) {
        const int k = wv * 2 + kk;
        const int s = (PROL + RITER * m + k) & (RING - 1);
        dma_row(xs, s, xlane, clampN(base0 + PROL + RITER * m + k, N));
    }
}

template <size_t... Rs>
__device__ __forceinline__ void load_w(float (&w)[RACC],
                                       const float* __restrict__ smb,
                                       int nbase, int minl, int N,
                                       std::index_sequence<Rs...>) {
    ((w[Rs] = smb[(size_t)clampN(nbase + (int)Rs, N) * WID + minl]), ...);
}

template <size_t... Rs>
__device__ __forceinline__ void zero_bad_w(float (&w)[RACC], int n0w, int lane,
                                           int N, std::index_sequence<Rs...>) {
    ((w[Rs] = ((unsigned)(n0w + (int)Rs - CEN + lane) < (unsigned)N)
                  ? w[Rs] : 0.0f),
     ...);
}

template <int J, size_t... Rs>
__device__ __forceinline__ void consume_j(f32x2 (&acc)[RACC],
                                          const float (&w)[RACC], f32x2 xv,
                                          std::index_sequence<Rs...>) {
    (([&] {
         constexpr int r = (int)Rs;
         if constexpr (J - r >= 0 && J - r < WID) {
             const float ws = rdlane(w[r], J - r);
             acc[r].x = fmaf(xv.x, ws, acc[r].x);
             acc[r].y = fmaf(xv.y, ws, acc[r].y);
         }
     }()),
     ...);
}

// read rel-rows (16m + 4rg + Js) -> slots (16m + 4rg + Js) & 63
template <size_t... Js>
__device__ __forceinline__ void stream_rows(f32x2 (&acc)[RACC],
                                            const float (&w)[RACC],
                                            const float* xs, int sbase,
                                            int cp, std::index_sequence<Js...>) {
    (([&] {
         const int s = (sbase + (int)Js) & (RING - 1);
         const f32x2 xv = ld2(xs + s * D_DIM + cp);
         consume_j<(int)Js>(acc, w, xv, std::make_index_sequence<RACC>{});
     }()),
     ...);
}

template <size_t... Rs>
__device__ __forceinline__ void store_all(const f32x2 (&acc)[RACC], float szv,
                                          float* __restrict__ ob,
                                          std::index_sequence<Rs...>) {
    (([&] {
         constexpr int r = (int)Rs;
         const float inv = __builtin_amdgcn_rcpf(fmaxf(rdlane(szv, r), 1e-6f));
         f32x2 o;
         o.x = acc[r].x * inv;
         o.y = acc[r].y * inv;
         __builtin_nontemporal_store(o, (f32x2*)(ob + (size_t)r * D_DIM));
     }()),
     ...);
}

__device__ __forceinline__ void iter_body(
    float* xs, const float* __restrict__ xlane, const float* __restrict__ smb,
    const float* __restrict__ szb, float* __restrict__ obl, int n0, int m,
    int N, int wv, int rg, int lane, int cp, float (&wcur)[RACC],
    float (&wnxt)[RACC], float& szcur, float& sznxt, int minl) {
    // phase 1: issue next-tile DMA + next-iter weight/size prefetch
    if (m < NI - 1)
        stage_iter(xs, xlane, n0 - CEN, m, N, wv);
    __builtin_amdgcn_sched_barrier(0);
    const int n1 = n0 + RITER * (m + 1) + rg * RACC;
    load_w(wnxt, smb, n1, minl, N, std::make_index_sequence<RACC>{});
    sznxt = szb[clampN(n1 + (lane & 3), N)];
    __builtin_amdgcn_sched_barrier(0);

    // phase 2: compute current 16 rows (4 per row-group) from the ring
    const int n0w = n0 + RITER * m + rg * RACC;
    if (n0w < CEN || n0w + RACC - 1 + CEN >= N)      // boundary iters only
        zero_bad_w(wcur, n0w, lane, N, std::make_index_sequence<RACC>{});

    f32x2 acc[RACC] = {};
    stream_rows(acc, wcur, xs, RITER * m + rg * RACC, cp,
                std::make_index_sequence<XROWS>{});
    store_all(acc, szcur, obl + (size_t)n0w * D_DIM,
              std::make_index_sequence<RACC>{});

    __syncthreads();   // full drain: spill-proof, ~0 cost here (R24)
}

__global__ __launch_bounds__(BLKT) void local_enc_kernel(
    const float* __restrict__ x, const float* __restrict__ sizev,
    const float* __restrict__ sm, float* __restrict__ out, int N) {
    __shared__ float xs[RING * D_DIM];     // 64 rows x 1KB = 64 KB

    // XCD swizzle: XCD k owns batch k, strips consecutive -> L2-local
    const int bid   = blockIdx.x;
    const int swz   = (bid & 7) * 64 + (bid >> 3);
    const int strip = swz & 63;
    const int b     = swz >> 6;
    const int n0    = strip * CHUNK;
    const int tid   = threadIdx.x;
    const int wv    = tid >> 6;            // 0..7
    const int lane  = tid & 63;
    const int rg    = wv >> 1;             // row-group 0..3 (4 rows each)
    const int ch    = wv & 1;              // column half
    const int cp    = ch * 128 + lane * 2; // this thread's column pair

    const size_t bN = (size_t)b * (size_t)N;
    const float* __restrict__ xlane = x + bN * D_DIM + lane * 4;
    const float* __restrict__ smb   = sm + bN * WID;
    const float* __restrict__ szb   = sizev + bN;
    float* __restrict__ obl         = out + bN * D_DIM + cp;

    // prologue: stage first 48 rows + load iter-0 weights/sizes
    stage_prol(xs, xlane, n0 - CEN, N, wv, std::make_index_sequence<PROL / 8>{});
    const int minl = (lane < WID) ? lane : (WID - 1);
    float wA[RACC], wB[RACC];
    float szA, szB;
    load_w(wA, smb, n0 + rg * RACC, minl, N, std::make_index_sequence<RACC>{});
    szA = szb[clampN(n0 + rg * RACC + (lane & 3), N)];
    __syncthreads();

#pragma unroll 1
    for (int mp = 0; mp < NI / 2; ++mp) {
        const int m0 = 2 * mp;
        iter_body(xs, xlane, smb, szb, obl, n0, m0, N, wv, rg, lane, cp,
                  wA, wB, szA, szB, minl);
        iter_body(xs, xlane, smb, szb, obl, n0, m0 + 1, N, wv, rg, lane, cp,
                  wB, wA, szB, szA, minl);
    }
}

extern "C" void kernel_launch(void* const* d_in, const int* in_sizes, int n_in,
                              void* d_out, int out_size, void* d_ws, size_t ws_size,
                              hipStream_t stream) {
    const float* x  = (const float*)d_in[0];
    const float* sz = (const float*)d_in[1];
    const float* sm = (const float*)d_in[2];
    float* out = (float*)d_out;

    const int B = 8;
    const int N = 16384;

    dim3 grid((N / CHUNK) * B, 1, 1);   // 64 x 8 = 512 blocks, XCD-swizzled
    dim3 block(BLKT, 1, 1);
    local_enc_kernel<<<grid, block, 0, stream>>>(x, sz, sm, out, N);
}

// Round 34
// 54.400 us; speedup vs baseline: 1.1695x; 1.1695x over previous
//
#include <hip/hip_runtime.h>
#include <utility>

#define D_DIM 256
#define WID   33
#define CEN   16
#define RACC  4                    // output rows per thread (per wave-group)
#define XROWS (RACC + 2 * CEN)     // 36 x-rows read per thread per iter
#define RITER 16                   // output rows per iteration (4 waves x 4)
#define NI    16                   // iterations per block
#define CHUNK (RITER * NI)         // 256 output rows per block
#define RING  64                   // ring rows = 64 KB LDS (2 blocks/CU)
#define PROL  48                   // prologue staged rows (= RITER + 32)

// R33 lesson (symmetric with R29): VALU/elem beats TLP — revert to R32.
// R32 residual theory: NT stores ack from HBM (~1000cy); the per-iter
// __syncthreads drains vmcnt(0) INCLUDING the 4 just-issued NT stores ->
// a serialized store-ack bubble every iter (pre-NT, stores ack'd from L2,
// which is why R24's counted wait showed no gain). Fix: counted barrier.
// Ops younger than the 4 DMAs = 4 w + 1 sz loads + 4 NT stores = 9 ->
// s_waitcnt vmcnt(9) retires exactly the DMAs; stores fly across the
// barrier. R24 ran this accounting at VGPR=88 no-spill and passed.

typedef float f32x4 __attribute__((ext_vector_type(4)));

__device__ __forceinline__ float rdlane(float v, int l) {
    return __uint_as_float(__builtin_amdgcn_readlane(__float_as_uint(v), l));
}

__device__ __forceinline__ int clampN(int p, int N) {
    return p < 0 ? 0 : (p >= N ? N - 1 : p);
}

__device__ __forceinline__ f32x4 ld4(const float* p) {
    return *(const f32x4*)p;
}

__device__ __forceinline__ void dma_row(float* xs, int slot,
                                        const float* __restrict__ xlane,
                                        int row) {
    __builtin_amdgcn_global_load_lds(
        (const __attribute__((address_space(1))) void*)(xlane +
                                                        (size_t)row * D_DIM),
        (__attribute__((address_space(3))) void*)(xs + slot * D_DIM), 16, 0, 0);
}

template <size_t... Ss>
__device__ __forceinline__ void stage_prol(float* xs,
                                           const float* __restrict__ xlane,
                                           int base0, int N, int wv,
                                           std::index_sequence<Ss...>) {
    (([&] {
         const int s = wv * (PROL / 4) + (int)Ss;      // 12 rows per wave
         dma_row(xs, s, xlane, clampN(base0 + s, N));
     }()),
     ...);
}

// stage 16 rows (4 per wave): row n0+32+16m+k -> slot (48+16m+k) & 63
__device__ __forceinline__ void stage_iter(float* xs,
                                           const float* __restrict__ xlane,
                                           int base0, int m, int N, int wv) {
#pragma unroll
    for (int kk = 0; kk < 4; ++kk) {
        const int k = wv * 4 + kk;
        const int s = (PROL + RITER * m + k) & (RING - 1);
        dma_row(xs, s, xlane, clampN(base0 + PROL + RITER * m + k, N));
    }
}

template <size_t... Rs>
__device__ __forceinline__ void load_w(float (&w)[RACC],
                                       const float* __restrict__ smb,
                                       int nbase, int minl, int N,
                                       std::index_sequence<Rs...>) {
    ((w[Rs] = smb[(size_t)clampN(nbase + (int)Rs, N) * WID + minl]), ...);
}

template <size_t... Rs>
__device__ __forceinline__ void zero_bad_w(float (&w)[RACC], int n0w, int lane,
                                           int N, std::index_sequence<Rs...>) {
    ((w[Rs] = ((unsigned)(n0w + (int)Rs - CEN + lane) < (unsigned)N)
                  ? w[Rs] : 0.0f),
     ...);
}

template <int J, size_t... Rs>
__device__ __forceinline__ void consume_j(f32x4 (&acc)[RACC],
                                          const float (&w)[RACC], f32x4 xv,
                                          std::index_sequence<Rs...>) {
    (([&] {
         constexpr int r = (int)Rs;
         if constexpr (J - r >= 0 && J - r < WID) {
             const float ws = rdlane(w[r], J - r);
             acc[r].x = fmaf(xv.x, ws, acc[r].x);
             acc[r].y = fmaf(xv.y, ws, acc[r].y);
             acc[r].z = fmaf(xv.z, ws, acc[r].z);
             acc[r].w = fmaf(xv.w, ws, acc[r].w);
         }
     }()),
     ...);
}

// read row (16m + 4wv - 16 + Js) -> slot (16m + 4wv + Js) & 63
template <size_t... Js>
__device__ __forceinline__ void stream_rows(f32x4 (&acc)[RACC],
                                            const float (&w)[RACC],
                                            const float* xs, int sbase,
                                            int lane4,
                                            std::index_sequence<Js...>) {
    (([&] {
         const int s = (sbase + (int)Js) & (RING - 1);
         const f32x4 xv = ld4(xs + s * D_DIM + lane4);
         consume_j<(int)Js>(acc, w, xv, std::make_index_sequence<RACC>{});
     }()),
     ...);
}

template <size_t... Rs>
__device__ __forceinline__ void store_all(const f32x4 (&acc)[RACC], float szv,
                                          float* __restrict__ ob,
                                          std::index_sequence<Rs...>) {
    (([&] {
         constexpr int r = (int)Rs;
         const float inv = __builtin_amdgcn_rcpf(fmaxf(rdlane(szv, r), 1e-6f));
         f32x4 o;
         o.x = acc[r].x * inv; o.y = acc[r].y * inv;
         o.z = acc[r].z * inv; o.w = acc[r].w * inv;
         __builtin_nontemporal_store(o, (f32x4*)(ob + (size_t)r * D_DIM));
     }()),
     ...);
}

__device__ __forceinline__ void iter_body(
    float* xs, const float* __restrict__ xlane, const float* __restrict__ smb,
    const float* __restrict__ szb, float* __restrict__ obl, int n0, int m,
    int N, int wv, int lane, int lane4, float (&wcur)[RACC],
    float (&wnxt)[RACC], float& szcur, float& sznxt, int minl) {
    // phase 1: issue next-tile DMA first (vmcnt accounting relies on order)
    if (m < NI - 1)
        stage_iter(xs, xlane, n0 - CEN, m, N, wv);
    __builtin_amdgcn_sched_barrier(0);
    const int n1 = n0 + RITER * (m + 1) + wv * RACC;
    load_w(wnxt, smb, n1, minl, N, std::make_index_sequence<RACC>{});
    sznxt = szb[clampN(n1 + (lane & 3), N)];
    __builtin_amdgcn_sched_barrier(0);

    // phase 2: compute current 16 rows (4 per wave) from the ring
    const int n0w = n0 + RITER * m + wv * RACC;
    if (n0w < CEN || n0w + RACC - 1 + CEN >= N)      // boundary iters only
        zero_bad_w(wcur, n0w, lane, N, std::make_index_sequence<RACC>{});

    f32x4 acc[RACC] = {};
    stream_rows(acc, wcur, xs, RITER * m + wv * RACC, lane4,
                std::make_index_sequence<XROWS>{});
    store_all(acc, szcur, obl + (size_t)n0w * D_DIM,
              std::make_index_sequence<RACC>{});

    // counted barrier: wait only for this iter's 4 DMAs (4 w + 1 sz loads
    // + 4 NT stores are younger = 9); NT stores stay in flight to HBM.
    __builtin_amdgcn_sched_barrier(0);
    asm volatile("s_waitcnt vmcnt(9)" ::: "memory");
    __builtin_amdgcn_s_barrier();
    __builtin_amdgcn_sched_barrier(0);
}

__global__ __launch_bounds__(256) void local_enc_kernel(
    const float* __restrict__ x, const float* __restrict__ sizev,
    const float* __restrict__ sm, float* __restrict__ out, int N) {
    __shared__ float xs[RING * D_DIM];     // 64 rows x 1KB = 64 KB

    // XCD swizzle: XCD k owns batch k, strips consecutive -> L2-local
    const int bid   = blockIdx.x;
    const int swz   = (bid & 7) * 64 + (bid >> 3);
    const int strip = swz & 63;
    const int b     = swz >> 6;
    const int n0    = strip * CHUNK;
    const int tid   = threadIdx.x;
    const int wv    = tid >> 6;            // 0..3 -> row-group
    const int lane  = tid & 63;
    const int lane4 = lane * 4;            // this thread's 4 columns

    const size_t bN = (size_t)b * (size_t)N;
    const float* __restrict__ xlane = x + bN * D_DIM + lane4;
    const float* __restrict__ smb   = sm + bN * WID;
    const float* __restrict__ szb   = sizev + bN;
    float* __restrict__ obl         = out + bN * D_DIM + lane4;

    // prologue: stage first 48 rows + load iter-0 weights/sizes
    stage_prol(xs, xlane, n0 - CEN, N, wv, std::make_index_sequence<PROL / 4>{});
    const int minl = (lane < WID) ? lane : (WID - 1);
    float wA[RACC], wB[RACC];
    float szA, szB;
    load_w(wA, smb, n0 + wv * RACC, minl, N, std::make_index_sequence<RACC>{});
    szA = szb[clampN(n0 + wv * RACC + (lane & 3), N)];
    __syncthreads();                       // one-time full drain is fine

#pragma unroll 1
    for (int mp = 0; mp < NI / 2; ++mp) {
        const int m0 = 2 * mp;
        iter_body(xs, xlane, smb, szb, obl, n0, m0, N, wv, lane, lane4,
                  wA, wB, szA, szB, minl);
        iter_body(xs, xlane, smb, szb, obl, n0, m0 + 1, N, wv, lane, lane4,
                  wB, wA, szB, szA, minl);
    }
}

extern "C" void kernel_launch(void* const* d_in, const int* in_sizes, int n_in,
                              void* d_out, int out_size, void* d_ws, size_t ws_size,
                              hipStream_t stream) {
    const float* x  = (const float*)d_in[0];
    const float* sz = (const float*)d_in[1];
    const float* sm = (const float*)d_in[2];
    float* out = (float*)d_out;

    const int B = 8;
    const int N = 16384;

    dim3 grid((N / CHUNK) * B, 1, 1);   // 64 x 8 = 512 blocks, XCD-swizzled
    dim3 block(256, 1, 1);
    local_enc_kernel<<<grid, block, 0, stream>>>(x, sz, sm, out, N);
}